// Round 9
// baseline (296.386 us; speedup 1.0000x reference)
//
#include <hip/hip_runtime.h>

typedef unsigned short u16;
typedef unsigned long long u64;
typedef __bf16 bf16x8 __attribute__((ext_vector_type(8)));
typedef float f32x4 __attribute__((ext_vector_type(4)));

#define B_ 8
#define T_ 1024
#define D_ 512
#define H_ 8
#define DK_ 64
#define F_ 2048

__device__ __forceinline__ u16 f2bf(float f) {
    unsigned u = __float_as_uint(f);
    u += 0x7fffu + ((u >> 16) & 1u);   // RNE
    return (u16)(u >> 16);
}
__device__ __forceinline__ float bf2f(u16 v) {
    return __uint_as_float((unsigned)v << 16);
}

// ---------------- merged prep: transposes + bias pack + mask bits ----------------
__device__ __forceinline__ void tile_transcvt(
    const float* __restrict__ W, u16* __restrict__ WT, int K, int N, int k0, int n0,
    u16 (*t)[72])
{
    const int tid = threadIdx.x;
    const int r = tid >> 2, c4 = (tid & 3) * 16;
    const float* src = W + (size_t)(k0 + r) * N + n0 + c4;
#pragma unroll
    for (int j = 0; j < 16; j += 4) {
        float4 v = *(const float4*)(src + j);
        t[r][c4 + j]     = f2bf(v.x);
        t[r][c4 + j + 1] = f2bf(v.y);
        t[r][c4 + j + 2] = f2bf(v.z);
        t[r][c4 + j + 3] = f2bf(v.w);
    }
    __syncthreads();
    u16 tmp[16];
#pragma unroll
    for (int j = 0; j < 16; ++j) tmp[j] = t[c4 + j][r];
    u16* dst = WT + (size_t)(n0 + r) * K + k0 + c4;
    *(uint4*)dst       = *(uint4*)&tmp[0];
    *(uint4*)(dst + 8) = *(uint4*)&tmp[8];
}

// grid: 192 (wqkv 8x24) + 256 (W1 8x32) + 256 (W2 32x8) + 2048 (maskbits) = 2752
__global__ __launch_bounds__(256) void prep_all(
    const float* __restrict__ Wq, const float* __restrict__ Wk, const float* __restrict__ Wv,
    const float* __restrict__ bq, const float* __restrict__ bk, const float* __restrict__ bv,
    const float* __restrict__ W1, const float* __restrict__ W2,
    const float* __restrict__ mask,
    u16* __restrict__ WqkvT, u16* __restrict__ W1T, u16* __restrict__ W2T,
    float* __restrict__ bias, u64* __restrict__ Mb)
{
    __shared__ u16 t[64][72];
    const int blk = blockIdx.x;
    const int tid = threadIdx.x;
    if (blk < 192) {
        const int k0 = (blk & 7) * 64;
        const int n0 = (blk >> 3) * 64;
        const float* W = (n0 < 512) ? Wq : (n0 < 1024 ? Wk : Wv);
        if (k0 == 0 && tid < 64) {
            int n = n0 + tid;
            bias[n] = (n < 512) ? bq[n] : (n < 1024 ? bk[n - 512] : bv[n - 1024]);
        }
        const int r = tid >> 2, c4 = (tid & 3) * 16;
        const float* src = W + (size_t)(k0 + r) * 512 + (n0 & 511) + c4;
#pragma unroll
        for (int j = 0; j < 16; j += 4) {
            float4 v = *(const float4*)(src + j);
            t[r][c4 + j]     = f2bf(v.x);
            t[r][c4 + j + 1] = f2bf(v.y);
            t[r][c4 + j + 2] = f2bf(v.z);
            t[r][c4 + j + 3] = f2bf(v.w);
        }
        __syncthreads();
        u16 tmp[16];
#pragma unroll
        for (int j = 0; j < 16; ++j) tmp[j] = t[c4 + j][r];
        u16* dst = WqkvT + (size_t)(n0 + r) * 512 + k0 + c4;
        *(uint4*)dst       = *(uint4*)&tmp[0];
        *(uint4*)(dst + 8) = *(uint4*)&tmp[8];
    } else if (blk < 448) {
        const int idx = blk - 192;                 // W1: K=512, N=2048, grid 8x32
        tile_transcvt(W1, W1T, 512, 2048, (idx & 7) * 64, (idx >> 3) * 64, t);
    } else if (blk < 704) {
        const int idx = blk - 448;                 // W2: K=2048, N=512, grid 32x8
        tile_transcvt(W2, W2T, 2048, 512, (idx & 31) * 64, (idx >> 5) * 64, t);
    } else {
        const int idx = blk - 704;                 // maskbits
        int gw = (idx * 256 + tid) >> 6;
        int lane = tid & 63;
#pragma unroll
        for (int i = 0; i < 16; ++i) {
            size_t chunk = (size_t)gw * 16 + i;
            float v = mask[chunk * 64 + lane];
            u64 bm = __ballot(v > 0.5f);
            if (lane == 0) Mb[chunk] = bm;
        }
    }
}

// ---------------- LayerNorm (wave per row, D=512 = 64 lanes * 8) ----------------
template<int XBF, int RBF, int OB, int OF>
__global__ __launch_bounds__(256) void ln_t(
    const void* __restrict__ Xv, const void* __restrict__ Rv,
    const float* __restrict__ g, const float* __restrict__ bt,
    u16* __restrict__ ob, float* __restrict__ of)
{
    int wave = threadIdx.x >> 6, lane = threadIdx.x & 63;
    int row = blockIdx.x * 4 + wave;
    size_t base = (size_t)row * D_ + lane * 8;
    int c0 = lane * 8;
    float v[8];
    if (XBF) {
        const u16* X = (const u16*)Xv;
        uint4 a = *(const uint4*)(X + base);
        u16 tu[8]; *(uint4*)tu = a;
#pragma unroll
        for (int j = 0; j < 8; ++j) v[j] = bf2f(tu[j]);
    } else {
        const float* X = (const float*)Xv;
        float4 a0 = *(const float4*)(X + base);
        float4 a1 = *(const float4*)(X + base + 4);
        v[0]=a0.x; v[1]=a0.y; v[2]=a0.z; v[3]=a0.w;
        v[4]=a1.x; v[5]=a1.y; v[6]=a1.z; v[7]=a1.w;
    }
    if (Rv) {
        if (RBF) {
            const u16* R = (const u16*)Rv;
            uint4 a = *(const uint4*)(R + base);
            u16 tu[8]; *(uint4*)tu = a;
#pragma unroll
            for (int j = 0; j < 8; ++j) v[j] += bf2f(tu[j]);
        } else {
            const float* R = (const float*)Rv;
            float4 r0 = *(const float4*)(R + base);
            float4 r1 = *(const float4*)(R + base + 4);
            v[0]+=r0.x; v[1]+=r0.y; v[2]+=r0.z; v[3]+=r0.w;
            v[4]+=r1.x; v[5]+=r1.y; v[6]+=r1.z; v[7]+=r1.w;
        }
    }
    float s = 0.f, q = 0.f;
#pragma unroll
    for (int j = 0; j < 8; ++j) { s += v[j]; q += v[j] * v[j]; }
#pragma unroll
    for (int off = 32; off > 0; off >>= 1) {
        s += __shfl_xor(s, off);
        q += __shfl_xor(q, off);
    }
    float mu = s * (1.0f / D_);
    float var = q * (1.0f / D_) - mu * mu;
    float rstd = rsqrtf(var + 1e-3f);
    float y[8];
#pragma unroll
    for (int j = 0; j < 8; ++j) y[j] = (v[j] - mu) * rstd * g[c0 + j] + bt[c0 + j];
    if (OB) {
        u16 t[8];
#pragma unroll
        for (int j = 0; j < 8; ++j) t[j] = f2bf(y[j]);
        *(uint4*)(ob + base) = *(uint4*)t;
    }
    if (OF) {
        float4 o0, o1;
        o0.x=y[0]; o0.y=y[1]; o0.z=y[2]; o0.w=y[3];
        o1.x=y[4]; o1.y=y[5]; o1.z=y[6]; o1.w=y[7];
        *(float4*)(of + base) = o0;
        *(float4*)(of + base + 4) = o1;
    }
}

// ---------------- BM=64 double-buffered GEMM, XCD swizzle ----------------
template<int BN, int RELU, int OUT>
__global__ __launch_bounds__(256) void gemm64(
    const u16* __restrict__ A, const u16* __restrict__ BT,
    const float* __restrict__ bias, u16* __restrict__ Cb,
    float* __restrict__ Cf, int N, int K)
{
    constexpr int NI = BN / 32;               // n-tiles of 16 per wave
    __shared__ u16 As[2][64 * 32];
    __shared__ u16 Bs[2][BN * 32];
    const int nb = gridDim.x;
    const int flat = blockIdx.y * nb + blockIdx.x;
    const int xcd = flat & 7;
    const int idx = flat >> 3;                // [0, nb*16)
    const int nblk = idx >> 4;                // n-block
    const int mblk = xcd * 16 + (idx & 15);   // m-block: XCD-contiguous
    const int tid = threadIdx.x;
    const int wave = tid >> 6, lane = tid & 63;
    const int quad = lane >> 4, l16 = lane & 15;
    const int wr = wave >> 1, wc = wave & 1;
    const int rowBase = mblk * 64;
    const int colBase = nblk * BN;
    const int lr = lane >> 2;                 // row within 16-row chunk
    const int lc = (lane & 3) * 8;            // k offset (u16)
    const u16* Abase = A  + (size_t)(rowBase + lr) * K + lc;
    const u16* Bbase = BT + (size_t)(colBase + lr) * K + lc;

    auto stage = [&](int k0, int buf) {
        {
            const u16* gp = Abase + (size_t)(wave * 16) * K + k0;
            __builtin_amdgcn_global_load_lds(
                (const __attribute__((address_space(1))) unsigned int*)gp,
                (__attribute__((address_space(3))) unsigned int*)&As[buf][wave * 512],
                16, 0, 0);
        }
#pragma unroll
        for (int c = 0; c < BN / 64; ++c) {
            int chunk = wave * (BN / 64) + c;
            const u16* gp = Bbase + (size_t)(chunk * 16) * K + k0;
            __builtin_amdgcn_global_load_lds(
                (const __attribute__((address_space(1))) unsigned int*)gp,
                (__attribute__((address_space(3))) unsigned int*)&Bs[buf][chunk * 512],
                16, 0, 0);
        }
    };

    f32x4 acc[2][NI] = {};
    stage(0, 0);
    for (int k0 = 0; k0 < K; k0 += 32) {
        const int buf = (k0 >> 5) & 1;
        __syncthreads();                       // drains buf's loads (after prior compute)
        if (k0 + 32 < K) stage(k0 + 32, buf ^ 1);
        bf16x8 af[2], bfr[NI];
#pragma unroll
        for (int i = 0; i < 2; ++i)
            af[i] = *(const bf16x8*)&As[buf][(wr * 32 + i * 16 + l16) * 32 + quad * 8];
#pragma unroll
        for (int j = 0; j < NI; ++j)
            bfr[j] = *(const bf16x8*)&Bs[buf][(wc * (BN / 2) + j * 16 + l16) * 32 + quad * 8];
#pragma unroll
        for (int i = 0; i < 2; ++i)
#pragma unroll
            for (int j = 0; j < NI; ++j)
                acc[i][j] = __builtin_amdgcn_mfma_f32_16x16x32_bf16(af[i], bfr[j], acc[i][j], 0, 0, 0);
    }
#pragma unroll
    for (int i = 0; i < 2; ++i) {
        int row0 = rowBase + wr * 32 + i * 16 + quad * 4;
#pragma unroll
        for (int j = 0; j < NI; ++j) {
            int col = colBase + wc * (BN / 2) + j * 16 + l16;
            float bv = bias[col];
#pragma unroll
            for (int r = 0; r < 4; ++r) {
                float v = acc[i][j][r] + bv;
                if (RELU) v = fmaxf(v, 0.0f);
                if (OUT == 1) Cb[(size_t)(row0 + r) * N + col] = f2bf(v);
                else          Cf[(size_t)(row0 + r) * N + col] = v;
            }
        }
    }
}

// ---------------- V repack: QKV[b,t, 1024 + h*64 + d] -> Vt[(b*8+h)*64 + d][t] ----------------
__global__ __launch_bounds__(256) void vtrans(const u16* __restrict__ QKV, u16* __restrict__ Vt)
{
    int blk = blockIdx.x;           // 1024 = B*H * T/64
    int bh = blk >> 4;
    int t0 = (blk & 15) * 64;
    int b = bh >> 3, h = bh & 7;
    __shared__ u16 tile[64][72];
    int tid = threadIdx.x;
    int r = tid >> 2;
    int c = (tid & 3) * 16;
    const u16* src = QKV + ((size_t)(b * T_) + t0 + r) * (3 * D_) + 2 * D_ + h * DK_ + c;
    *(uint4*)&tile[r][c]     = *(const uint4*)(src);
    *(uint4*)&tile[r][c + 8] = *(const uint4*)(src + 8);
    __syncthreads();
    u16 tmp[16];
#pragma unroll
    for (int j = 0; j < 16; ++j) tmp[j] = tile[c + j][r];
    u16* dst = Vt + ((size_t)bh * DK_ + r) * T_ + t0 + c;
    *(uint4*)dst       = *(uint4*)&tmp[0];
    *(uint4*)(dst + 8) = *(uint4*)&tmp[8];
}

// ---------------- flash attention, transposed-output form ----------------
// Computes S^T = mfma(Kfrag, Qfrag) and O^T = mfma(Vfrag, Pfrag): the A-frag of X
// is the B-frag of X^T, so operand swap is free. Benefit: q-row lands in the
// MFMA column (lane-fixed l16) -> P store = 4x b64 (was 16 scalar u16), mask =
// 1 u64/lane/tile (was 4), l_i = 1 reg + 2 end-shuffles (was 4 regs + 16), and
// the output epilogue packs 4x b64 stores (was 16 scalar). exp folded to one
// v_fma + v_exp via exp2.
#define APAD 72
__global__ __launch_bounds__(256) void attn_kernel(
    const u16* __restrict__ QKV, const u16* __restrict__ Vt,
    const u64* __restrict__ Mb, u16* __restrict__ Out)
{
    const int flat = blockIdx.x + 16 * (blockIdx.y + 8 * blockIdx.z);
    const int xcd = flat & 7, slot = flat >> 3;
    const int bh = xcd * 8 + (slot >> 4);
    const int qt = slot & 15;
    const int b = bh >> 3, h = bh & 7;
    const int qBase = qt * 64;
    const int tid = threadIdx.x;
    const int wave = tid >> 6, lane = tid & 63;
    const int quad = lane >> 4, l16 = lane & 15;
    __shared__ u16 Ks[64][APAD];      // [s][dk]
    __shared__ u16 Vs[64][APAD];      // [d][s]
    __shared__ u16 Ps[4][16][APAD];   // per wave [m][s]  (m = q-row = l16)

    const int qRow = qBase + wave * 16 + l16;
    const u16* qptr = QKV + ((size_t)(b * T_) + qRow) * (3 * D_) + h * DK_;
    bf16x8 qf0 = *(const bf16x8*)(qptr + quad * 8);
    bf16x8 qf1 = *(const bf16x8*)(qptr + 32 + quad * 8);

    float l_i = 0.f;
    f32x4 o[4] = {{0,0,0,0},{0,0,0,0},{0,0,0,0},{0,0,0,0}};

    const int sr = tid >> 2;
    const int sc = (tid & 3) * 8;
    const u16* Kg = QKV + (size_t)(b * T_) * (3 * D_) + D_ + h * DK_;
    const u16* Vg = Vt + (size_t)(b * H_ + h) * DK_ * T_;
    const u64* Mg = Mb + ((size_t)(b * T_) + qRow) * (T_ / 64);   // one row per lane

    // prefetch tile 0 into registers
    uint4 kb0 = *(const uint4*)(Kg + (size_t)sr * (3 * D_) + sc);
    uint4 kb1 = *(const uint4*)(Kg + (size_t)sr * (3 * D_) + sc + 32);
    uint4 vb0 = *(const uint4*)(Vg + (size_t)sr * T_ + sc);
    uint4 vb1 = *(const uint4*)(Vg + (size_t)sr * T_ + sc + 32);

    for (int s0 = 0; s0 < T_; s0 += 64) {
        __syncthreads();                       // prior iter's LDS reads done
        *(uint4*)&Ks[sr][sc]      = kb0;
        *(uint4*)&Ks[sr][sc + 32] = kb1;
        *(uint4*)&Vs[sr][sc]      = vb0;
        *(uint4*)&Vs[sr][sc + 32] = vb1;
        __syncthreads();
        if (s0 + 64 < T_) {                    // prefetch next tile; lands next iter
            int s1 = s0 + 64;
            kb0 = *(const uint4*)(Kg + (size_t)(s1 + sr) * (3 * D_) + sc);
            kb1 = *(const uint4*)(Kg + (size_t)(s1 + sr) * (3 * D_) + sc + 32);
            vb0 = *(const uint4*)(Vg + (size_t)sr * T_ + s1 + sc);
            vb1 = *(const uint4*)(Vg + (size_t)sr * T_ + s1 + sc + 32);
        }

        const u64 m64 = Mg[s0 >> 6];           // this lane's q-row, 64 s-bits

#pragma unroll
        for (int st = 0; st < 4; ++st) {
            f32x4 s4 = {0.f, 0.f, 0.f, 0.f};
            bf16x8 kf0 = *(const bf16x8*)&Ks[st * 16 + l16][quad * 8];
            bf16x8 kf1 = *(const bf16x8*)&Ks[st * 16 + l16][32 + quad * 8];
            s4 = __builtin_amdgcn_mfma_f32_16x16x32_bf16(kf0, qf0, s4, 0, 0, 0);  // S^T tile
            s4 = __builtin_amdgcn_mfma_f32_16x16x32_bf16(kf1, qf1, s4, 0, 0, 0);
            u16 pk[4];
#pragma unroll
            for (int r = 0; r < 4; ++r) {
                int sl = st * 16 + quad * 4 + r;
                // exp(s/8 - 10) = exp2(s*0.125*log2e - 10*log2e)
                float p = exp2f(fmaf(s4[r], 0.1803368801f, -14.4269504089f));
                p = ((m64 >> sl) & 1ull) ? p : 0.0f;
                l_i += p;
                pk[r] = f2bf(p);
            }
            *(u64*)&Ps[wave][l16][st * 16 + quad * 4] = *(u64*)pk;   // b64 packed store
        }
        // Ps is wave-private: intra-wave lgkmcnt ordering suffices, no barrier.
        bf16x8 pf0 = *(const bf16x8*)&Ps[wave][l16][quad * 8];
        bf16x8 pf1 = *(const bf16x8*)&Ps[wave][l16][32 + quad * 8];
#pragma unroll
        for (int dt = 0; dt < 4; ++dt) {
            bf16x8 vf0 = *(const bf16x8*)&Vs[dt * 16 + l16][quad * 8];
            bf16x8 vf1 = *(const bf16x8*)&Vs[dt * 16 + l16][32 + quad * 8];
            o[dt] = __builtin_amdgcn_mfma_f32_16x16x32_bf16(vf0, pf0, o[dt], 0, 0, 0);  // O^T
            o[dt] = __builtin_amdgcn_mfma_f32_16x16x32_bf16(vf1, pf1, o[dt], 0, 0, 0);
        }
    }
    l_i += __shfl_xor(l_i, 16);
    l_i += __shfl_xor(l_i, 32);
    const float inv = 1.0f / l_i;
    // O^T C-layout: col = l16 = q-row (fixed per lane), row = dt*16 + quad*4 + r = d.
    u16* Ob = Out + ((size_t)(b * T_) + qRow) * D_ + h * DK_;
#pragma unroll
    for (int dt = 0; dt < 4; ++dt) {
        u16 t4[4];
#pragma unroll
        for (int r = 0; r < 4; ++r) t4[r] = f2bf(o[dt][r] * inv);
        *(u64*)&Ob[dt * 16 + quad * 4] = *(u64*)t4;   // 4 contiguous d, b64 store
    }
}

// ---------------- launch ----------------
extern "C" void kernel_launch(void* const* d_in, const int* in_sizes, int n_in,
                              void* d_out, int out_size, void* d_ws, size_t ws_size,
                              hipStream_t stream)
{
    const float* x       = (const float*)d_in[0];
    const float* mask    = (const float*)d_in[1];
    const float* ln_in_g = (const float*)d_in[2];
    const float* ln_in_b = (const float*)d_in[3];
    const float* Wq      = (const float*)d_in[4];
    const float* bq      = (const float*)d_in[5];
    const float* Wk      = (const float*)d_in[6];
    const float* bk      = (const float*)d_in[7];
    const float* Wv      = (const float*)d_in[8];
    const float* bv      = (const float*)d_in[9];
    const float* ln1_g   = (const float*)d_in[10];
    const float* ln1_b   = (const float*)d_in[11];
    const float* W1      = (const float*)d_in[12];
    const float* b1      = (const float*)d_in[13];
    const float* W2      = (const float*)d_in[14];
    const float* b2      = (const float*)d_in[15];
    const float* ln2_g   = (const float*)d_in[16];
    const float* ln2_b   = (const float*)d_in[17];
    float* out = (float*)d_out;

    char* ws = (char*)d_ws;
    size_t off = 0;
    auto alloc = [&](size_t bytes) -> void* {
        void* p = ws + off;
        off = (off + bytes + 255) & ~(size_t)255;
        return p;
    };
    u16*   WqkvT   = (u16*)alloc((size_t)1536 * 512 * 2);
    u16*   W1T     = (u16*)alloc((size_t)2048 * 512 * 2);
    u16*   W2T     = (u16*)alloc((size_t)512 * 2048 * 2);
    float* bias_q  = (float*)alloc(1536 * 4);
    u64*   Mb      = (u64*)alloc((size_t)B_ * T_ * (T_ / 64) * 8);
    u16*   h_bf    = (u16*)alloc((size_t)8192 * 512 * 2);
    u16*   QKV     = (u16*)alloc((size_t)8192 * 1536 * 2);
    u16*   Vt      = (u16*)alloc((size_t)B_ * H_ * DK_ * T_ * 2);
    u16*   attn_bf = (u16*)alloc((size_t)8192 * 512 * 2);
    u16*   a_bf    = (u16*)alloc((size_t)8192 * 512 * 2);
    u16*   f1      = (u16*)alloc((size_t)8192 * 2048 * 2);
    float* f2      = (float*)alloc((size_t)8192 * 512 * 4);
    if (off > ws_size) return;   // workspace too small; fail loud (output untouched)

    prep_all<<<2752, 256, 0, stream>>>(Wq, Wk, Wv, bq, bk, bv, W1, W2, mask,
                                       WqkvT, W1T, W2T, bias_q, Mb);

    // h = LN(x) -> bf16
    ln_t<0, 0, 1, 0><<<2048, 256, 0, stream>>>(
        x, nullptr, ln_in_g, ln_in_b, h_bf, nullptr);

    gemm64<128, 0, 1><<<dim3(12, 128), 256, 0, stream>>>(
        h_bf, WqkvT, bias_q, QKV, nullptr, 1536, 512);

    vtrans<<<1024, 256, 0, stream>>>(QKV, Vt);

    attn_kernel<<<dim3(16, 8, 8), 256, 0, stream>>>(QKV, Vt, Mb, attn_bf);

    // a = LN(attn + x) -> bf16
    ln_t<1, 0, 1, 0><<<2048, 256, 0, stream>>>(
        attn_bf, x, ln1_g, ln1_b, a_bf, nullptr);

    gemm64<128, 1, 1><<<dim3(16, 128), 256, 0, stream>>>(
        a_bf, W1T, b1, f1, nullptr, 2048, 512);

    gemm64<64, 0, 0><<<dim3(8, 128), 256, 0, stream>>>(
        f1, W2T, b2, nullptr, f2, 512, 2048);

    // out = LN(f2 + a)
    ln_t<0, 1, 0, 1><<<2048, 256, 0, stream>>>(
        f2, a_bf, ln2_g, ln2_b, nullptr, out);
}

// Round 10
// 287.046 us; speedup vs baseline: 1.0325x; 1.0325x over previous
//
#include <hip/hip_runtime.h>

typedef unsigned short u16;
typedef unsigned long long u64;
typedef __bf16 bf16x8 __attribute__((ext_vector_type(8)));
typedef float f32x4 __attribute__((ext_vector_type(4)));

#define B_ 8
#define T_ 1024
#define D_ 512
#define H_ 8
#define DK_ 64
#define F_ 2048

__device__ __forceinline__ u16 f2bf(float f) {
    unsigned u = __float_as_uint(f);
    u += 0x7fffu + ((u >> 16) & 1u);   // RNE
    return (u16)(u >> 16);
}
__device__ __forceinline__ float bf2f(u16 v) {
    return __uint_as_float((unsigned)v << 16);
}

// ---------------- merged prep: transposes + bias pack + mask bits ----------------
__device__ __forceinline__ void tile_transcvt(
    const float* __restrict__ W, u16* __restrict__ WT, int K, int N, int k0, int n0,
    u16 (*t)[72])
{
    const int tid = threadIdx.x;
    const int r = tid >> 2, c4 = (tid & 3) * 16;
    const float* src = W + (size_t)(k0 + r) * N + n0 + c4;
#pragma unroll
    for (int j = 0; j < 16; j += 4) {
        float4 v = *(const float4*)(src + j);
        t[r][c4 + j]     = f2bf(v.x);
        t[r][c4 + j + 1] = f2bf(v.y);
        t[r][c4 + j + 2] = f2bf(v.z);
        t[r][c4 + j + 3] = f2bf(v.w);
    }
    __syncthreads();
    u16 tmp[16];
#pragma unroll
    for (int j = 0; j < 16; ++j) tmp[j] = t[c4 + j][r];
    u16* dst = WT + (size_t)(n0 + r) * K + k0 + c4;
    *(uint4*)dst       = *(uint4*)&tmp[0];
    *(uint4*)(dst + 8) = *(uint4*)&tmp[8];
}

// grid: 192 (wqkv 8x24) + 256 (W1 8x32) + 256 (W2 32x8) + 2048 (maskbits) = 2752
__global__ __launch_bounds__(256) void prep_all(
    const float* __restrict__ Wq, const float* __restrict__ Wk, const float* __restrict__ Wv,
    const float* __restrict__ bq, const float* __restrict__ bk, const float* __restrict__ bv,
    const float* __restrict__ W1, const float* __restrict__ W2,
    const float* __restrict__ mask,
    u16* __restrict__ WqkvT, u16* __restrict__ W1T, u16* __restrict__ W2T,
    float* __restrict__ bias, u64* __restrict__ Mb)
{
    __shared__ u16 t[64][72];
    const int blk = blockIdx.x;
    const int tid = threadIdx.x;
    if (blk < 192) {
        const int k0 = (blk & 7) * 64;
        const int n0 = (blk >> 3) * 64;
        const float* W = (n0 < 512) ? Wq : (n0 < 1024 ? Wk : Wv);
        if (k0 == 0 && tid < 64) {
            int n = n0 + tid;
            bias[n] = (n < 512) ? bq[n] : (n < 1024 ? bk[n - 512] : bv[n - 1024]);
        }
        const int r = tid >> 2, c4 = (tid & 3) * 16;
        const float* src = W + (size_t)(k0 + r) * 512 + (n0 & 511) + c4;
#pragma unroll
        for (int j = 0; j < 16; j += 4) {
            float4 v = *(const float4*)(src + j);
            t[r][c4 + j]     = f2bf(v.x);
            t[r][c4 + j + 1] = f2bf(v.y);
            t[r][c4 + j + 2] = f2bf(v.z);
            t[r][c4 + j + 3] = f2bf(v.w);
        }
        __syncthreads();
        u16 tmp[16];
#pragma unroll
        for (int j = 0; j < 16; ++j) tmp[j] = t[c4 + j][r];
        u16* dst = WqkvT + (size_t)(n0 + r) * 512 + k0 + c4;
        *(uint4*)dst       = *(uint4*)&tmp[0];
        *(uint4*)(dst + 8) = *(uint4*)&tmp[8];
    } else if (blk < 448) {
        const int idx = blk - 192;                 // W1: K=512, N=2048, grid 8x32
        tile_transcvt(W1, W1T, 512, 2048, (idx & 7) * 64, (idx >> 3) * 64, t);
    } else if (blk < 704) {
        const int idx = blk - 448;                 // W2: K=2048, N=512, grid 32x8
        tile_transcvt(W2, W2T, 2048, 512, (idx & 31) * 64, (idx >> 5) * 64, t);
    } else {
        const int idx = blk - 704;                 // maskbits
        int gw = (idx * 256 + tid) >> 6;
        int lane = tid & 63;
#pragma unroll
        for (int i = 0; i < 16; ++i) {
            size_t chunk = (size_t)gw * 16 + i;
            float v = mask[chunk * 64 + lane];
            u64 bm = __ballot(v > 0.5f);
            if (lane == 0) Mb[chunk] = bm;
        }
    }
}

// ---------------- LayerNorm (wave per row, D=512 = 64 lanes * 8) ----------------
template<int XBF, int RBF, int OB, int OF>
__global__ __launch_bounds__(256) void ln_t(
    const void* __restrict__ Xv, const void* __restrict__ Rv,
    const float* __restrict__ g, const float* __restrict__ bt,
    u16* __restrict__ ob, float* __restrict__ of)
{
    int wave = threadIdx.x >> 6, lane = threadIdx.x & 63;
    int row = blockIdx.x * 4 + wave;
    size_t base = (size_t)row * D_ + lane * 8;
    int c0 = lane * 8;
    float v[8];
    if (XBF) {
        const u16* X = (const u16*)Xv;
        uint4 a = *(const uint4*)(X + base);
        u16 tu[8]; *(uint4*)tu = a;
#pragma unroll
        for (int j = 0; j < 8; ++j) v[j] = bf2f(tu[j]);
    } else {
        const float* X = (const float*)Xv;
        float4 a0 = *(const float4*)(X + base);
        float4 a1 = *(const float4*)(X + base + 4);
        v[0]=a0.x; v[1]=a0.y; v[2]=a0.z; v[3]=a0.w;
        v[4]=a1.x; v[5]=a1.y; v[6]=a1.z; v[7]=a1.w;
    }
    if (Rv) {
        if (RBF) {
            const u16* R = (const u16*)Rv;
            uint4 a = *(const uint4*)(R + base);
            u16 tu[8]; *(uint4*)tu = a;
#pragma unroll
            for (int j = 0; j < 8; ++j) v[j] += bf2f(tu[j]);
        } else {
            const float* R = (const float*)Rv;
            float4 r0 = *(const float4*)(R + base);
            float4 r1 = *(const float4*)(R + base + 4);
            v[0]+=r0.x; v[1]+=r0.y; v[2]+=r0.z; v[3]+=r0.w;
            v[4]+=r1.x; v[5]+=r1.y; v[6]+=r1.z; v[7]+=r1.w;
        }
    }
    float s = 0.f, q = 0.f;
#pragma unroll
    for (int j = 0; j < 8; ++j) { s += v[j]; q += v[j] * v[j]; }
#pragma unroll
    for (int off = 32; off > 0; off >>= 1) {
        s += __shfl_xor(s, off);
        q += __shfl_xor(q, off);
    }
    float mu = s * (1.0f / D_);
    float var = q * (1.0f / D_) - mu * mu;
    float rstd = rsqrtf(var + 1e-3f);
    float y[8];
#pragma unroll
    for (int j = 0; j < 8; ++j) y[j] = (v[j] - mu) * rstd * g[c0 + j] + bt[c0 + j];
    if (OB) {
        u16 t[8];
#pragma unroll
        for (int j = 0; j < 8; ++j) t[j] = f2bf(y[j]);
        *(uint4*)(ob + base) = *(uint4*)t;
    }
    if (OF) {
        float4 o0, o1;
        o0.x=y[0]; o0.y=y[1]; o0.z=y[2]; o0.w=y[3];
        o1.x=y[4]; o1.y=y[5]; o1.z=y[6]; o1.w=y[7];
        *(float4*)(of + base) = o0;
        *(float4*)(of + base + 4) = o1;
    }
}

// ---------------- BM=64 double-buffered GEMM, XCD swizzle ----------------
// OUT: 0 = fp32 store (+bias), 1 = bf16 store (+bias).
template<int BN, int RELU, int OUT>
__global__ __launch_bounds__(256) void gemm64(
    const u16* __restrict__ A, const u16* __restrict__ BT,
    const float* __restrict__ bias, u16* __restrict__ Cb,
    float* __restrict__ Cf, int N, int K)
{
    constexpr int NI = BN / 32;               // n-tiles of 16 per wave
    __shared__ u16 As[2][64 * 32];
    __shared__ u16 Bs[2][BN * 32];
    const int nb = gridDim.x;
    const int flat = blockIdx.y * nb + blockIdx.x;
    const int xcd = flat & 7;
    const int idx = flat >> 3;                // [0, nb*16)
    const int nblk = idx >> 4;                // n-block
    const int mblk = xcd * 16 + (idx & 15);   // m-block: XCD-contiguous
    const int tid = threadIdx.x;
    const int wave = tid >> 6, lane = tid & 63;
    const int quad = lane >> 4, l16 = lane & 15;
    const int wr = wave >> 1, wc = wave & 1;
    const int rowBase = mblk * 64;
    const int colBase = nblk * BN;
    const int lr = lane >> 2;                 // row within 16-row chunk
    const int lc = (lane & 3) * 8;            // k offset (u16)
    const u16* Abase = A  + (size_t)(rowBase + lr) * K + lc;
    const u16* Bbase = BT + (size_t)(colBase + lr) * K + lc;

    auto stage = [&](int k0, int buf) {
        {
            const u16* gp = Abase + (size_t)(wave * 16) * K + k0;
            __builtin_amdgcn_global_load_lds(
                (const __attribute__((address_space(1))) unsigned int*)gp,
                (__attribute__((address_space(3))) unsigned int*)&As[buf][wave * 512],
                16, 0, 0);
        }
#pragma unroll
        for (int c = 0; c < BN / 64; ++c) {
            int chunk = wave * (BN / 64) + c;
            const u16* gp = Bbase + (size_t)(chunk * 16) * K + k0;
            __builtin_amdgcn_global_load_lds(
                (const __attribute__((address_space(1))) unsigned int*)gp,
                (__attribute__((address_space(3))) unsigned int*)&Bs[buf][chunk * 512],
                16, 0, 0);
        }
    };

    f32x4 acc[2][NI] = {};
    stage(0, 0);
    for (int k0 = 0; k0 < K; k0 += 32) {
        const int buf = (k0 >> 5) & 1;
        __syncthreads();                       // drains buf's loads (after prior compute)
        if (k0 + 32 < K) stage(k0 + 32, buf ^ 1);
        bf16x8 af[2], bfr[NI];
#pragma unroll
        for (int i = 0; i < 2; ++i)
            af[i] = *(const bf16x8*)&As[buf][(wr * 32 + i * 16 + l16) * 32 + quad * 8];
#pragma unroll
        for (int j = 0; j < NI; ++j)
            bfr[j] = *(const bf16x8*)&Bs[buf][(wc * (BN / 2) + j * 16 + l16) * 32 + quad * 8];
#pragma unroll
        for (int i = 0; i < 2; ++i)
#pragma unroll
            for (int j = 0; j < NI; ++j)
                acc[i][j] = __builtin_amdgcn_mfma_f32_16x16x32_bf16(af[i], bfr[j], acc[i][j], 0, 0, 0);
    }
#pragma unroll
    for (int i = 0; i < 2; ++i) {
        int row0 = rowBase + wr * 32 + i * 16 + quad * 4;
#pragma unroll
        for (int j = 0; j < NI; ++j) {
            int col = colBase + wc * (BN / 2) + j * 16 + l16;
            float bv = bias[col];
#pragma unroll
            for (int r = 0; r < 4; ++r) {
                float v = acc[i][j][r] + bv;
                if (RELU) v = fmaxf(v, 0.0f);
                if (OUT == 1) Cb[(size_t)(row0 + r) * N + col] = f2bf(v);
                else          Cf[(size_t)(row0 + r) * N + col] = v;
            }
        }
    }
}

// ---------------- V repack: QKV[b,t, 1024 + h*64 + d] -> Vt[(b*8+h)*64 + d][t] ----------------
__global__ __launch_bounds__(256) void vtrans(const u16* __restrict__ QKV, u16* __restrict__ Vt)
{
    int blk = blockIdx.x;           // 1024 = B*H * T/64
    int bh = blk >> 4;
    int t0 = (blk & 15) * 64;
    int b = bh >> 3, h = bh & 7;
    __shared__ u16 tile[64][72];
    int tid = threadIdx.x;
    int r = tid >> 2;
    int c = (tid & 3) * 16;
    const u16* src = QKV + ((size_t)(b * T_) + t0 + r) * (3 * D_) + 2 * D_ + h * DK_ + c;
    *(uint4*)&tile[r][c]     = *(const uint4*)(src);
    *(uint4*)&tile[r][c + 8] = *(const uint4*)(src + 8);
    __syncthreads();
    u16 tmp[16];
#pragma unroll
    for (int j = 0; j < 16; ++j) tmp[j] = tile[c + j][r];
    u16* dst = Vt + ((size_t)bh * DK_ + r) * T_ + t0 + c;
    *(uint4*)dst       = *(uint4*)&tmp[0];
    *(uint4*)(dst + 8) = *(uint4*)&tmp[8];
}

// ---------------- flash attention (R8 structure, proven 49.5us; exp2 fold only) ----------------
// Hard rule from R5/R6/R9: keep VGPR <= 64 (occupancy cliff at 68).
#define APAD 72
__global__ __launch_bounds__(256) void attn_kernel(
    const u16* __restrict__ QKV, const u16* __restrict__ Vt,
    const u64* __restrict__ Mb, u16* __restrict__ Out)
{
    const int flat = blockIdx.x + 16 * (blockIdx.y + 8 * blockIdx.z);
    const int xcd = flat & 7, slot = flat >> 3;
    const int bh = xcd * 8 + (slot >> 4);
    const int qt = slot & 15;
    const int b = bh >> 3, h = bh & 7;
    const int qBase = qt * 64;
    const int tid = threadIdx.x;
    const int wave = tid >> 6, lane = tid & 63;
    const int quad = lane >> 4, l16 = lane & 15;
    __shared__ u16 Ks[64][APAD];      // [s][dk]
    __shared__ u16 Vs[64][APAD];      // [d][s]
    __shared__ u16 Ps[4][16][APAD];   // per wave [m][s]

    const int qRow = qBase + wave * 16 + l16;
    const u16* qptr = QKV + ((size_t)(b * T_) + qRow) * (3 * D_) + h * DK_;
    bf16x8 qf0 = *(const bf16x8*)(qptr + quad * 8);
    bf16x8 qf1 = *(const bf16x8*)(qptr + 32 + quad * 8);

    float l_i[4] = {0.f, 0.f, 0.f, 0.f};
    f32x4 o[4] = {{0,0,0,0},{0,0,0,0},{0,0,0,0},{0,0,0,0}};

    const int sr = tid >> 2;
    const int sc = (tid & 3) * 8;
    const u16* Kg = QKV + (size_t)(b * T_) * (3 * D_) + D_ + h * DK_;
    const u16* Vg = Vt + (size_t)(b * H_ + h) * DK_ * T_;
    const u64* Mg = Mb + ((size_t)(b * T_) + qBase + wave * 16 + quad * 4) * (T_ / 64);

    // prefetch tile 0 into registers
    uint4 kb0 = *(const uint4*)(Kg + (size_t)sr * (3 * D_) + sc);
    uint4 kb1 = *(const uint4*)(Kg + (size_t)sr * (3 * D_) + sc + 32);
    uint4 vb0 = *(const uint4*)(Vg + (size_t)sr * T_ + sc);
    uint4 vb1 = *(const uint4*)(Vg + (size_t)sr * T_ + sc + 32);

    for (int s0 = 0; s0 < T_; s0 += 64) {
        __syncthreads();                       // prior iter's LDS reads done
        *(uint4*)&Ks[sr][sc]      = kb0;
        *(uint4*)&Ks[sr][sc + 32] = kb1;
        *(uint4*)&Vs[sr][sc]      = vb0;
        *(uint4*)&Vs[sr][sc + 32] = vb1;
        __syncthreads();
        if (s0 + 64 < T_) {                    // prefetch next tile; lands next iter
            int s1 = s0 + 64;
            kb0 = *(const uint4*)(Kg + (size_t)(s1 + sr) * (3 * D_) + sc);
            kb1 = *(const uint4*)(Kg + (size_t)(s1 + sr) * (3 * D_) + sc + 32);
            vb0 = *(const uint4*)(Vg + (size_t)sr * T_ + s1 + sc);
            vb1 = *(const uint4*)(Vg + (size_t)sr * T_ + s1 + sc + 32);
        }

        u64 m64[4];
#pragma unroll
        for (int r = 0; r < 4; ++r) m64[r] = Mg[(size_t)r * (T_ / 64) + (s0 >> 6)];

#pragma unroll
        for (int n = 0; n < 4; ++n) {
            f32x4 s4 = {0.f, 0.f, 0.f, 0.f};
            bf16x8 kf0 = *(const bf16x8*)&Ks[n * 16 + l16][quad * 8];
            bf16x8 kf1 = *(const bf16x8*)&Ks[n * 16 + l16][32 + quad * 8];
            s4 = __builtin_amdgcn_mfma_f32_16x16x32_bf16(qf0, kf0, s4, 0, 0, 0);
            s4 = __builtin_amdgcn_mfma_f32_16x16x32_bf16(qf1, kf1, s4, 0, 0, 0);
#pragma unroll
            for (int r = 0; r < 4; ++r) {
                // exp(s/8 - 10) = exp2(s*(0.125*log2e) - 10*log2e)  (one fma + one exp)
                float p = exp2f(fmaf(s4[r], 0.1803368801f, -14.4269504089f));
                p = ((m64[r] >> (n * 16 + l16)) & 1ull) ? p : 0.0f;
                l_i[r] += p;
                Ps[wave][quad * 4 + r][n * 16 + l16] = f2bf(p);
            }
        }
        // Ps is wave-private: intra-wave lgkmcnt ordering suffices, no barrier.
        bf16x8 pf0 = *(const bf16x8*)&Ps[wave][l16][quad * 8];
        bf16x8 pf1 = *(const bf16x8*)&Ps[wave][l16][32 + quad * 8];
#pragma unroll
        for (int dt = 0; dt < 4; ++dt) {
            bf16x8 vf0 = *(const bf16x8*)&Vs[dt * 16 + l16][quad * 8];
            bf16x8 vf1 = *(const bf16x8*)&Vs[dt * 16 + l16][32 + quad * 8];
            o[dt] = __builtin_amdgcn_mfma_f32_16x16x32_bf16(pf0, vf0, o[dt], 0, 0, 0);
            o[dt] = __builtin_amdgcn_mfma_f32_16x16x32_bf16(pf1, vf1, o[dt], 0, 0, 0);
        }
    }
#pragma unroll
    for (int off = 1; off < 16; off <<= 1) {
#pragma unroll
        for (int r = 0; r < 4; ++r) l_i[r] += __shfl_xor(l_i[r], off);
    }
    float inv[4];
#pragma unroll
    for (int r = 0; r < 4; ++r) inv[r] = 1.0f / l_i[r];
    const int orow = qBase + wave * 16 + quad * 4;
    u16* Ob = Out + ((size_t)(b * T_) + orow) * D_ + h * DK_;
#pragma unroll
    for (int dt = 0; dt < 4; ++dt) {
#pragma unroll
        for (int r = 0; r < 4; ++r)
            Ob[(size_t)r * D_ + dt * 16 + l16] = f2bf(o[dt][r] * inv[r]);
    }
}

// ---------------- launch ----------------
extern "C" void kernel_launch(void* const* d_in, const int* in_sizes, int n_in,
                              void* d_out, int out_size, void* d_ws, size_t ws_size,
                              hipStream_t stream)
{
    const float* x       = (const float*)d_in[0];
    const float* mask    = (const float*)d_in[1];
    const float* ln_in_g = (const float*)d_in[2];
    const float* ln_in_b = (const float*)d_in[3];
    const float* Wq      = (const float*)d_in[4];
    const float* bq      = (const float*)d_in[5];
    const float* Wk      = (const float*)d_in[6];
    const float* bk      = (const float*)d_in[7];
    const float* Wv      = (const float*)d_in[8];
    const float* bv      = (const float*)d_in[9];
    const float* ln1_g   = (const float*)d_in[10];
    const float* ln1_b   = (const float*)d_in[11];
    const float* W1      = (const float*)d_in[12];
    const float* b1      = (const float*)d_in[13];
    const float* W2      = (const float*)d_in[14];
    const float* b2      = (const float*)d_in[15];
    const float* ln2_g   = (const float*)d_in[16];
    const float* ln2_b   = (const float*)d_in[17];
    float* out = (float*)d_out;

    char* ws = (char*)d_ws;
    size_t off = 0;
    auto alloc = [&](size_t bytes) -> void* {
        void* p = ws + off;
        off = (off + bytes + 255) & ~(size_t)255;
        return p;
    };
    u16*   WqkvT   = (u16*)alloc((size_t)1536 * 512 * 2);
    u16*   W1T     = (u16*)alloc((size_t)2048 * 512 * 2);
    u16*   W2T     = (u16*)alloc((size_t)512 * 2048 * 2);
    float* bias_q  = (float*)alloc(1536 * 4);
    u64*   Mb      = (u64*)alloc((size_t)B_ * T_ * (T_ / 64) * 8);
    u16*   h_bf    = (u16*)alloc((size_t)8192 * 512 * 2);
    u16*   QKV     = (u16*)alloc((size_t)8192 * 1536 * 2);
    u16*   Vt      = (u16*)alloc((size_t)B_ * H_ * DK_ * T_ * 2);
    u16*   attn_bf = (u16*)alloc((size_t)8192 * 512 * 2);
    u16*   a_bf    = (u16*)alloc((size_t)8192 * 512 * 2);
    u16*   f1      = (u16*)alloc((size_t)8192 * 2048 * 2);
    u16*   f2_bf   = (u16*)alloc((size_t)8192 * 512 * 2);
    if (off > ws_size) return;   // workspace too small; fail loud (output untouched)

    prep_all<<<2752, 256, 0, stream>>>(Wq, Wk, Wv, bq, bk, bv, W1, W2, mask,
                                       WqkvT, W1T, W2T, bias_q, Mb);

    // h = LN(x) -> bf16
    ln_t<0, 0, 1, 0><<<2048, 256, 0, stream>>>(
        x, nullptr, ln_in_g, ln_in_b, h_bf, nullptr);

    gemm64<128, 0, 1><<<dim3(12, 128), 256, 0, stream>>>(
        h_bf, WqkvT, bias_q, QKV, nullptr, 1536, 512);

    vtrans<<<1024, 256, 0, stream>>>(QKV, Vt);

    attn_kernel<<<dim3(16, 8, 8), 256, 0, stream>>>(QKV, Vt, Mb, attn_bf);

    // a = LN(attn + x) -> bf16
    ln_t<1, 0, 1, 0><<<2048, 256, 0, stream>>>(
        attn_bf, x, ln1_g, ln1_b, a_bf, nullptr);

    gemm64<128, 1, 1><<<dim3(16, 128), 256, 0, stream>>>(
        a_bf, W1T, b1, f1, nullptr, 2048, 512);

    // FFN2 -> bf16 (halves f2 write + ln2 read traffic)
    gemm64<64, 0, 1><<<dim3(8, 128), 256, 0, stream>>>(
        f1, W2T, b2, f2_bf, nullptr, 512, 2048);

    // out = LN(f2 + a)
    ln_t<1, 1, 0, 1><<<2048, 256, 0, stream>>>(
        f2_bf, a_bf, ln2_g, ln2_b, nullptr, out);
}

// Round 11
// 281.807 us; speedup vs baseline: 1.0517x; 1.0186x over previous
//
#include <hip/hip_runtime.h>

typedef unsigned short u16;
typedef unsigned long long u64;
typedef __bf16 bf16x8 __attribute__((ext_vector_type(8)));
typedef float f32x4 __attribute__((ext_vector_type(4)));

#define B_ 8
#define T_ 1024
#define D_ 512
#define H_ 8
#define DK_ 64
#define F_ 2048

__device__ __forceinline__ u16 f2bf(float f) {
    unsigned u = __float_as_uint(f);
    u += 0x7fffu + ((u >> 16) & 1u);   // RNE
    return (u16)(u >> 16);
}
__device__ __forceinline__ float bf2f(u16 v) {
    return __uint_as_float((unsigned)v << 16);
}

// ---------------- merged prep: transposes + bias pack + mask bits + LN0 ----------------
__device__ __forceinline__ void tile_transcvt(
    const float* __restrict__ W, u16* __restrict__ WT, int K, int N, int k0, int n0,
    u16 (*t)[72])
{
    const int tid = threadIdx.x;
    const int r = tid >> 2, c4 = (tid & 3) * 16;
    const float* src = W + (size_t)(k0 + r) * N + n0 + c4;
#pragma unroll
    for (int j = 0; j < 16; j += 4) {
        float4 v = *(const float4*)(src + j);
        t[r][c4 + j]     = f2bf(v.x);
        t[r][c4 + j + 1] = f2bf(v.y);
        t[r][c4 + j + 2] = f2bf(v.z);
        t[r][c4 + j + 3] = f2bf(v.w);
    }
    __syncthreads();
    u16 tmp[16];
#pragma unroll
    for (int j = 0; j < 16; ++j) tmp[j] = t[c4 + j][r];
    u16* dst = WT + (size_t)(n0 + r) * K + k0 + c4;
    *(uint4*)dst       = *(uint4*)&tmp[0];
    *(uint4*)(dst + 8) = *(uint4*)&tmp[8];
}

// grid: 192 (wqkv) + 256 (W1) + 256 (W2) + 2048 (maskbits) + 2048 (LN0 + x->bf16) = 4800
__global__ __launch_bounds__(256) void prep_all(
    const float* __restrict__ Wq, const float* __restrict__ Wk, const float* __restrict__ Wv,
    const float* __restrict__ bq, const float* __restrict__ bk, const float* __restrict__ bv,
    const float* __restrict__ W1, const float* __restrict__ W2,
    const float* __restrict__ mask, const float* __restrict__ x,
    const float* __restrict__ ln_in_g, const float* __restrict__ ln_in_b,
    u16* __restrict__ WqkvT, u16* __restrict__ W1T, u16* __restrict__ W2T,
    float* __restrict__ bias, u64* __restrict__ Mb,
    u16* __restrict__ h_bf, u16* __restrict__ x_bf)
{
    __shared__ u16 t[64][72];
    const int blk = blockIdx.x;
    const int tid = threadIdx.x;
    if (blk < 192) {
        const int k0 = (blk & 7) * 64;
        const int n0 = (blk >> 3) * 64;
        const float* W = (n0 < 512) ? Wq : (n0 < 1024 ? Wk : Wv);
        if (k0 == 0 && tid < 64) {
            int n = n0 + tid;
            bias[n] = (n < 512) ? bq[n] : (n < 1024 ? bk[n - 512] : bv[n - 1024]);
        }
        const int r = tid >> 2, c4 = (tid & 3) * 16;
        const float* src = W + (size_t)(k0 + r) * 512 + (n0 & 511) + c4;
#pragma unroll
        for (int j = 0; j < 16; j += 4) {
            float4 v = *(const float4*)(src + j);
            t[r][c4 + j]     = f2bf(v.x);
            t[r][c4 + j + 1] = f2bf(v.y);
            t[r][c4 + j + 2] = f2bf(v.z);
            t[r][c4 + j + 3] = f2bf(v.w);
        }
        __syncthreads();
        u16 tmp[16];
#pragma unroll
        for (int j = 0; j < 16; ++j) tmp[j] = t[c4 + j][r];
        u16* dst = WqkvT + (size_t)(n0 + r) * 512 + k0 + c4;
        *(uint4*)dst       = *(uint4*)&tmp[0];
        *(uint4*)(dst + 8) = *(uint4*)&tmp[8];
    } else if (blk < 448) {
        const int idx = blk - 192;                 // W1: K=512, N=2048, grid 8x32
        tile_transcvt(W1, W1T, 512, 2048, (idx & 7) * 64, (idx >> 3) * 64, t);
    } else if (blk < 704) {
        const int idx = blk - 448;                 // W2: K=2048, N=512, grid 32x8
        tile_transcvt(W2, W2T, 2048, 512, (idx & 31) * 64, (idx >> 5) * 64, t);
    } else if (blk < 2752) {
        const int idx = blk - 704;                 // maskbits
        int gw = (idx * 256 + tid) >> 6;
        int lane = tid & 63;
#pragma unroll
        for (int i = 0; i < 16; ++i) {
            size_t chunk = (size_t)gw * 16 + i;
            float v = mask[chunk * 64 + lane];
            u64 bm = __ballot(v > 0.5f);
            if (lane == 0) Mb[chunk] = bm;
        }
    } else {
        // LN0: h = LN(x) -> h_bf ; also x -> x_bf (for bf16 residual in ln1)
        const int idx = blk - 2752;
        int wave = tid >> 6, lane = tid & 63;
        int row = idx * 4 + wave;
        size_t base = (size_t)row * D_ + lane * 8;
        int c0 = lane * 8;
        float v[8];
        float4 a0 = *(const float4*)(x + base);
        float4 a1 = *(const float4*)(x + base + 4);
        v[0]=a0.x; v[1]=a0.y; v[2]=a0.z; v[3]=a0.w;
        v[4]=a1.x; v[5]=a1.y; v[6]=a1.z; v[7]=a1.w;
        u16 xb[8];
#pragma unroll
        for (int j = 0; j < 8; ++j) xb[j] = f2bf(v[j]);
        *(uint4*)(x_bf + base) = *(uint4*)xb;
        float s = 0.f, q = 0.f;
#pragma unroll
        for (int j = 0; j < 8; ++j) { s += v[j]; q += v[j] * v[j]; }
#pragma unroll
        for (int off = 32; off > 0; off >>= 1) {
            s += __shfl_xor(s, off);
            q += __shfl_xor(q, off);
        }
        float mu = s * (1.0f / D_);
        float var = q * (1.0f / D_) - mu * mu;
        float rstd = rsqrtf(var + 1e-3f);
        u16 hb[8];
#pragma unroll
        for (int j = 0; j < 8; ++j)
            hb[j] = f2bf((v[j] - mu) * rstd * ln_in_g[c0 + j] + ln_in_b[c0 + j]);
        *(uint4*)(h_bf + base) = *(uint4*)hb;
    }
}

// ---------------- LayerNorm (wave per row, D=512 = 64 lanes * 8) ----------------
template<int XBF, int RBF, int OB, int OF>
__global__ __launch_bounds__(256) void ln_t(
    const void* __restrict__ Xv, const void* __restrict__ Rv,
    const float* __restrict__ g, const float* __restrict__ bt,
    u16* __restrict__ ob, float* __restrict__ of)
{
    int wave = threadIdx.x >> 6, lane = threadIdx.x & 63;
    int row = blockIdx.x * 4 + wave;
    size_t base = (size_t)row * D_ + lane * 8;
    int c0 = lane * 8;
    float v[8];
    if (XBF) {
        const u16* X = (const u16*)Xv;
        uint4 a = *(const uint4*)(X + base);
        u16 tu[8]; *(uint4*)tu = a;
#pragma unroll
        for (int j = 0; j < 8; ++j) v[j] = bf2f(tu[j]);
    } else {
        const float* X = (const float*)Xv;
        float4 a0 = *(const float4*)(X + base);
        float4 a1 = *(const float4*)(X + base + 4);
        v[0]=a0.x; v[1]=a0.y; v[2]=a0.z; v[3]=a0.w;
        v[4]=a1.x; v[5]=a1.y; v[6]=a1.z; v[7]=a1.w;
    }
    if (Rv) {
        if (RBF) {
            const u16* R = (const u16*)Rv;
            uint4 a = *(const uint4*)(R + base);
            u16 tu[8]; *(uint4*)tu = a;
#pragma unroll
            for (int j = 0; j < 8; ++j) v[j] += bf2f(tu[j]);
        } else {
            const float* R = (const float*)Rv;
            float4 r0 = *(const float4*)(R + base);
            float4 r1 = *(const float4*)(R + base + 4);
            v[0]+=r0.x; v[1]+=r0.y; v[2]+=r0.z; v[3]+=r0.w;
            v[4]+=r1.x; v[5]+=r1.y; v[6]+=r1.z; v[7]+=r1.w;
        }
    }
    float s = 0.f, q = 0.f;
#pragma unroll
    for (int j = 0; j < 8; ++j) { s += v[j]; q += v[j] * v[j]; }
#pragma unroll
    for (int off = 32; off > 0; off >>= 1) {
        s += __shfl_xor(s, off);
        q += __shfl_xor(q, off);
    }
    float mu = s * (1.0f / D_);
    float var = q * (1.0f / D_) - mu * mu;
    float rstd = rsqrtf(var + 1e-3f);
    float y[8];
#pragma unroll
    for (int j = 0; j < 8; ++j) y[j] = (v[j] - mu) * rstd * g[c0 + j] + bt[c0 + j];
    if (OB) {
        u16 t[8];
#pragma unroll
        for (int j = 0; j < 8; ++j) t[j] = f2bf(y[j]);
        *(uint4*)(ob + base) = *(uint4*)t;
    }
    if (OF) {
        float4 o0, o1;
        o0.x=y[0]; o0.y=y[1]; o0.z=y[2]; o0.w=y[3];
        o1.x=y[4]; o1.y=y[5]; o1.z=y[6]; o1.w=y[7];
        *(float4*)(of + base) = o0;
        *(float4*)(of + base + 4) = o1;
    }
}

// ---------------- BM=64 double-buffered GEMM, XCD swizzle ----------------
// OUT: 0 = fp32 store (+bias), 1 = bf16 store (+bias).
template<int BN, int RELU, int OUT>
__global__ __launch_bounds__(256) void gemm64(
    const u16* __restrict__ A, const u16* __restrict__ BT,
    const float* __restrict__ bias, u16* __restrict__ Cb,
    float* __restrict__ Cf, int N, int K)
{
    constexpr int NI = BN / 32;               // n-tiles of 16 per wave
    __shared__ u16 As[2][64 * 32];
    __shared__ u16 Bs[2][BN * 32];
    const int nb = gridDim.x;
    const int flat = blockIdx.y * nb + blockIdx.x;
    const int xcd = flat & 7;
    const int idx = flat >> 3;                // [0, nb*16)
    const int nblk = idx >> 4;                // n-block
    const int mblk = xcd * 16 + (idx & 15);   // m-block: XCD-contiguous
    const int tid = threadIdx.x;
    const int wave = tid >> 6, lane = tid & 63;
    const int quad = lane >> 4, l16 = lane & 15;
    const int wr = wave >> 1, wc = wave & 1;
    const int rowBase = mblk * 64;
    const int colBase = nblk * BN;
    const int lr = lane >> 2;                 // row within 16-row chunk
    const int lc = (lane & 3) * 8;            // k offset (u16)
    const u16* Abase = A  + (size_t)(rowBase + lr) * K + lc;
    const u16* Bbase = BT + (size_t)(colBase + lr) * K + lc;

    auto stage = [&](int k0, int buf) {
        {
            const u16* gp = Abase + (size_t)(wave * 16) * K + k0;
            __builtin_amdgcn_global_load_lds(
                (const __attribute__((address_space(1))) unsigned int*)gp,
                (__attribute__((address_space(3))) unsigned int*)&As[buf][wave * 512],
                16, 0, 0);
        }
#pragma unroll
        for (int c = 0; c < BN / 64; ++c) {
            int chunk = wave * (BN / 64) + c;
            const u16* gp = Bbase + (size_t)(chunk * 16) * K + k0;
            __builtin_amdgcn_global_load_lds(
                (const __attribute__((address_space(1))) unsigned int*)gp,
                (__attribute__((address_space(3))) unsigned int*)&Bs[buf][chunk * 512],
                16, 0, 0);
        }
    };

    f32x4 acc[2][NI] = {};
    stage(0, 0);
    for (int k0 = 0; k0 < K; k0 += 32) {
        const int buf = (k0 >> 5) & 1;
        __syncthreads();                       // drains buf's loads (after prior compute)
        if (k0 + 32 < K) stage(k0 + 32, buf ^ 1);
        bf16x8 af[2], bfr[NI];
#pragma unroll
        for (int i = 0; i < 2; ++i)
            af[i] = *(const bf16x8*)&As[buf][(wr * 32 + i * 16 + l16) * 32 + quad * 8];
#pragma unroll
        for (int j = 0; j < NI; ++j)
            bfr[j] = *(const bf16x8*)&Bs[buf][(wc * (BN / 2) + j * 16 + l16) * 32 + quad * 8];
#pragma unroll
        for (int i = 0; i < 2; ++i)
#pragma unroll
            for (int j = 0; j < NI; ++j)
                acc[i][j] = __builtin_amdgcn_mfma_f32_16x16x32_bf16(af[i], bfr[j], acc[i][j], 0, 0, 0);
    }
#pragma unroll
    for (int i = 0; i < 2; ++i) {
        int row0 = rowBase + wr * 32 + i * 16 + quad * 4;
#pragma unroll
        for (int j = 0; j < NI; ++j) {
            int col = colBase + wc * (BN / 2) + j * 16 + l16;
            float bv = bias[col];
#pragma unroll
            for (int r = 0; r < 4; ++r) {
                float v = acc[i][j][r] + bv;
                if (RELU) v = fmaxf(v, 0.0f);
                if (OUT == 1) Cb[(size_t)(row0 + r) * N + col] = f2bf(v);
                else          Cf[(size_t)(row0 + r) * N + col] = v;
            }
        }
    }
}

// ---------------- V repack: QKV[b,t, 1024 + h*64 + d] -> Vt[(b*8+h)*64 + d][t] ----------------
__global__ __launch_bounds__(256) void vtrans(const u16* __restrict__ QKV, u16* __restrict__ Vt)
{
    int blk = blockIdx.x;           // 1024 = B*H * T/64
    int bh = blk >> 4;
    int t0 = (blk & 15) * 64;
    int b = bh >> 3, h = bh & 7;
    __shared__ u16 tile[64][72];
    int tid = threadIdx.x;
    int r = tid >> 2;
    int c = (tid & 3) * 16;
    const u16* src = QKV + ((size_t)(b * T_) + t0 + r) * (3 * D_) + 2 * D_ + h * DK_ + c;
    *(uint4*)&tile[r][c]     = *(const uint4*)(src);
    *(uint4*)&tile[r][c + 8] = *(const uint4*)(src + 8);
    __syncthreads();
    u16 tmp[16];
#pragma unroll
    for (int j = 0; j < 16; ++j) tmp[j] = tile[c + j][r];
    u16* dst = Vt + ((size_t)bh * DK_ + r) * T_ + t0 + c;
    *(uint4*)dst       = *(uint4*)&tmp[0];
    *(uint4*)(dst + 8) = *(uint4*)&tmp[8];
}

// ---------------- flash attention (exact R8 structure, proven 49.5us) ----------------
// Hard rules: VGPR <= 64 (cliff at 68); __expf not libm exp2f (R10: +5us VALU).
#define APAD 72
__global__ __launch_bounds__(256) void attn_kernel(
    const u16* __restrict__ QKV, const u16* __restrict__ Vt,
    const u64* __restrict__ Mb, u16* __restrict__ Out)
{
    const int flat = blockIdx.x + 16 * (blockIdx.y + 8 * blockIdx.z);
    const int xcd = flat & 7, slot = flat >> 3;
    const int bh = xcd * 8 + (slot >> 4);
    const int qt = slot & 15;
    const int b = bh >> 3, h = bh & 7;
    const int qBase = qt * 64;
    const int tid = threadIdx.x;
    const int wave = tid >> 6, lane = tid & 63;
    const int quad = lane >> 4, l16 = lane & 15;
    __shared__ u16 Ks[64][APAD];      // [s][dk]
    __shared__ u16 Vs[64][APAD];      // [d][s]
    __shared__ u16 Ps[4][16][APAD];   // per wave [m][s]

    const int qRow = qBase + wave * 16 + l16;
    const u16* qptr = QKV + ((size_t)(b * T_) + qRow) * (3 * D_) + h * DK_;
    bf16x8 qf0 = *(const bf16x8*)(qptr + quad * 8);
    bf16x8 qf1 = *(const bf16x8*)(qptr + 32 + quad * 8);

    float l_i[4] = {0.f, 0.f, 0.f, 0.f};
    f32x4 o[4] = {{0,0,0,0},{0,0,0,0},{0,0,0,0},{0,0,0,0}};

    const int sr = tid >> 2;
    const int sc = (tid & 3) * 8;
    const u16* Kg = QKV + (size_t)(b * T_) * (3 * D_) + D_ + h * DK_;
    const u16* Vg = Vt + (size_t)(b * H_ + h) * DK_ * T_;
    const u64* Mg = Mb + ((size_t)(b * T_) + qBase + wave * 16 + quad * 4) * (T_ / 64);

    // prefetch tile 0 into registers
    uint4 kb0 = *(const uint4*)(Kg + (size_t)sr * (3 * D_) + sc);
    uint4 kb1 = *(const uint4*)(Kg + (size_t)sr * (3 * D_) + sc + 32);
    uint4 vb0 = *(const uint4*)(Vg + (size_t)sr * T_ + sc);
    uint4 vb1 = *(const uint4*)(Vg + (size_t)sr * T_ + sc + 32);

    for (int s0 = 0; s0 < T_; s0 += 64) {
        __syncthreads();                       // prior iter's LDS reads done
        *(uint4*)&Ks[sr][sc]      = kb0;
        *(uint4*)&Ks[sr][sc + 32] = kb1;
        *(uint4*)&Vs[sr][sc]      = vb0;
        *(uint4*)&Vs[sr][sc + 32] = vb1;
        __syncthreads();
        if (s0 + 64 < T_) {                    // prefetch next tile; lands next iter
            int s1 = s0 + 64;
            kb0 = *(const uint4*)(Kg + (size_t)(s1 + sr) * (3 * D_) + sc);
            kb1 = *(const uint4*)(Kg + (size_t)(s1 + sr) * (3 * D_) + sc + 32);
            vb0 = *(const uint4*)(Vg + (size_t)sr * T_ + s1 + sc);
            vb1 = *(const uint4*)(Vg + (size_t)sr * T_ + s1 + sc + 32);
        }

        u64 m64[4];
#pragma unroll
        for (int r = 0; r < 4; ++r) m64[r] = Mg[(size_t)r * (T_ / 64) + (s0 >> 6)];

#pragma unroll
        for (int n = 0; n < 4; ++n) {
            f32x4 s4 = {0.f, 0.f, 0.f, 0.f};
            bf16x8 kf0 = *(const bf16x8*)&Ks[n * 16 + l16][quad * 8];
            bf16x8 kf1 = *(const bf16x8*)&Ks[n * 16 + l16][32 + quad * 8];
            s4 = __builtin_amdgcn_mfma_f32_16x16x32_bf16(qf0, kf0, s4, 0, 0, 0);
            s4 = __builtin_amdgcn_mfma_f32_16x16x32_bf16(qf1, kf1, s4, 0, 0, 0);
#pragma unroll
            for (int r = 0; r < 4; ++r) {
                float p = __expf(fmaf(s4[r], 0.125f, -10.0f));
                p = ((m64[r] >> (n * 16 + l16)) & 1ull) ? p : 0.0f;
                l_i[r] += p;
                Ps[wave][quad * 4 + r][n * 16 + l16] = f2bf(p);
            }
        }
        // Ps is wave-private: intra-wave lgkmcnt ordering suffices, no barrier.
        bf16x8 pf0 = *(const bf16x8*)&Ps[wave][l16][quad * 8];
        bf16x8 pf1 = *(const bf16x8*)&Ps[wave][l16][32 + quad * 8];
#pragma unroll
        for (int dt = 0; dt < 4; ++dt) {
            bf16x8 vf0 = *(const bf16x8*)&Vs[dt * 16 + l16][quad * 8];
            bf16x8 vf1 = *(const bf16x8*)&Vs[dt * 16 + l16][32 + quad * 8];
            o[dt] = __builtin_amdgcn_mfma_f32_16x16x32_bf16(pf0, vf0, o[dt], 0, 0, 0);
            o[dt] = __builtin_amdgcn_mfma_f32_16x16x32_bf16(pf1, vf1, o[dt], 0, 0, 0);
        }
    }
#pragma unroll
    for (int off = 1; off < 16; off <<= 1) {
#pragma unroll
        for (int r = 0; r < 4; ++r) l_i[r] += __shfl_xor(l_i[r], off);
    }
    float inv[4];
#pragma unroll
    for (int r = 0; r < 4; ++r) inv[r] = 1.0f / l_i[r];
    const int orow = qBase + wave * 16 + quad * 4;
    u16* Ob = Out + ((size_t)(b * T_) + orow) * D_ + h * DK_;
#pragma unroll
    for (int dt = 0; dt < 4; ++dt) {
#pragma unroll
        for (int r = 0; r < 4; ++r)
            Ob[(size_t)r * D_ + dt * 16 + l16] = f2bf(o[dt][r] * inv[r]);
    }
}

// ---------------- launch ----------------
extern "C" void kernel_launch(void* const* d_in, const int* in_sizes, int n_in,
                              void* d_out, int out_size, void* d_ws, size_t ws_size,
                              hipStream_t stream)
{
    const float* x       = (const float*)d_in[0];
    const float* mask    = (const float*)d_in[1];
    const float* ln_in_g = (const float*)d_in[2];
    const float* ln_in_b = (const float*)d_in[3];
    const float* Wq      = (const float*)d_in[4];
    const float* bq      = (const float*)d_in[5];
    const float* Wk      = (const float*)d_in[6];
    const float* bk      = (const float*)d_in[7];
    const float* Wv      = (const float*)d_in[8];
    const float* bv      = (const float*)d_in[9];
    const float* ln1_g   = (const float*)d_in[10];
    const float* ln1_b   = (const float*)d_in[11];
    const float* W1      = (const float*)d_in[12];
    const float* b1      = (const float*)d_in[13];
    const float* W2      = (const float*)d_in[14];
    const float* b2      = (const float*)d_in[15];
    const float* ln2_g   = (const float*)d_in[16];
    const float* ln2_b   = (const float*)d_in[17];
    float* out = (float*)d_out;

    char* ws = (char*)d_ws;
    size_t off = 0;
    auto alloc = [&](size_t bytes) -> void* {
        void* p = ws + off;
        off = (off + bytes + 255) & ~(size_t)255;
        return p;
    };
    u16*   WqkvT   = (u16*)alloc((size_t)1536 * 512 * 2);
    u16*   W1T     = (u16*)alloc((size_t)2048 * 512 * 2);
    u16*   W2T     = (u16*)alloc((size_t)512 * 2048 * 2);
    float* bias_q  = (float*)alloc(1536 * 4);
    u64*   Mb      = (u64*)alloc((size_t)B_ * T_ * (T_ / 64) * 8);
    u16*   h_bf    = (u16*)alloc((size_t)8192 * 512 * 2);
    u16*   x_bf    = (u16*)alloc((size_t)8192 * 512 * 2);
    u16*   QKV     = (u16*)alloc((size_t)8192 * 1536 * 2);
    u16*   Vt      = (u16*)alloc((size_t)B_ * H_ * DK_ * T_ * 2);
    u16*   attn_bf = (u16*)alloc((size_t)8192 * 512 * 2);
    u16*   a_bf    = (u16*)alloc((size_t)8192 * 512 * 2);
    u16*   f1      = (u16*)alloc((size_t)8192 * 2048 * 2);
    u16*   f2_bf   = (u16*)alloc((size_t)8192 * 512 * 2);
    if (off > ws_size) return;   // workspace too small; fail loud (output untouched)

    // prep + LN0 fused (independent work, one dispatch)
    prep_all<<<4800, 256, 0, stream>>>(Wq, Wk, Wv, bq, bk, bv, W1, W2, mask,
                                       x, ln_in_g, ln_in_b,
                                       WqkvT, W1T, W2T, bias_q, Mb, h_bf, x_bf);

    gemm64<128, 0, 1><<<dim3(12, 128), 256, 0, stream>>>(
        h_bf, WqkvT, bias_q, QKV, nullptr, 1536, 512);

    vtrans<<<1024, 256, 0, stream>>>(QKV, Vt);

    attn_kernel<<<dim3(16, 8, 8), 256, 0, stream>>>(QKV, Vt, Mb, attn_bf);

    // a = LN(attn + x) -> bf16 (x residual now bf16)
    ln_t<1, 1, 1, 0><<<2048, 256, 0, stream>>>(
        attn_bf, x_bf, ln1_g, ln1_b, a_bf, nullptr);

    gemm64<128, 1, 1><<<dim3(16, 128), 256, 0, stream>>>(
        a_bf, W1T, b1, f1, nullptr, 2048, 512);

    // FFN2 -> bf16
    gemm64<64, 0, 1><<<dim3(8, 128), 256, 0, stream>>>(
        f1, W2T, b2, f2_bf, nullptr, 512, 2048);

    // out = LN(f2 + a)
    ln_t<1, 1, 0, 1><<<2048, 256, 0, stream>>>(
        f2_bf, a_bf, ln2_g, ln2_b, nullptr, out);
}